// Round 2
// baseline (4959.604 us; speedup 1.0000x reference)
//
#include <hip/hip_runtime.h>
#include <cstdint>
#include <cstddef>

// GraphConvolution: out = (A_sparse @ x) @ W^T + b
// N=100000, E=3.2M, D=256.
// Pipeline: histogram -> scan -> CSR scatter (packed col|row) -> permute W
//           -> fused edge-parallel gather (LDS atomics) + fp32 GEMM.
#define D 256
#define NPB 32           // nodes per fused block (100000 % 32 == 0)
#define SCAN_CHUNK 2048  // 256 threads * 8 items
#define COLMASK 0x07FFFFFF

__global__ void k_hist(const int* __restrict__ erow, int* __restrict__ counts, int e) {
    int i = blockIdx.x * blockDim.x + threadIdx.x;
    if (i < e) atomicAdd(&counts[erow[i]], 1);
}

__global__ void k_scan1(const int* __restrict__ counts, int* __restrict__ row_start,
                        int* __restrict__ blk_sums, int n) {
    __shared__ int sd[256];
    int tid = threadIdx.x;
    int base = blockIdx.x * SCAN_CHUNK + tid * 8;
    int v[8];
    int s = 0;
#pragma unroll
    for (int i = 0; i < 8; ++i) {
        int idx = base + i;
        v[i] = (idx < n) ? counts[idx] : 0;
        s += v[i];
    }
    sd[tid] = s;
    __syncthreads();
    for (int off = 1; off < 256; off <<= 1) {
        int t = (tid >= off) ? sd[tid - off] : 0;
        __syncthreads();
        sd[tid] += t;
        __syncthreads();
    }
    int run = sd[tid] - s;
    if (tid == 255) blk_sums[blockIdx.x] = sd[255];
#pragma unroll
    for (int i = 0; i < 8; ++i) {
        int idx = base + i;
        if (idx < n) row_start[idx] = run;
        run += v[i];
    }
}

__global__ void k_scan2(int* __restrict__ blk_sums, int* __restrict__ row_start, int nch, int n) {
    __shared__ int sd[64];
    int tid = threadIdx.x;
    if (tid < nch) sd[tid] = blk_sums[tid];
    __syncthreads();
    if (tid == 0) {
        int run = 0;
        for (int b = 0; b < nch; ++b) { int t = sd[b]; sd[b] = run; run += t; }
        row_start[n] = run;  // == E
    }
    __syncthreads();
    if (tid < nch) blk_sums[tid] = sd[tid];
}

__global__ void k_scan3(int* __restrict__ row_start, const int* __restrict__ blk_sums, int n) {
    int i = blockIdx.x * blockDim.x + threadIdx.x;
    if (i < n) row_start[i] += blk_sums[i >> 11];
}

// pack: low 27 bits = col, high 5 bits = row % 32 (local row within fused block)
__global__ void k_scatter(const int* __restrict__ erow, const int* __restrict__ ecol,
                          const float* __restrict__ eval, const int* __restrict__ row_start,
                          int* __restrict__ cursor, int2* __restrict__ sedge, int e) {
    int i = blockIdx.x * blockDim.x + threadIdx.x;
    if (i < e) {
        int r = erow[i];
        int p = row_start[r] + atomicAdd(&cursor[r], 1);
        int packed = ecol[i] | ((r & 31) << 27);
        sedge[p] = make_int2(packed, __float_as_int(eval[i]));
    }
}

// W_perm[o][p] = W[o][k] with p = (k&3)*64 + (k>>2)  (matches agg LDS swizzle)
__global__ void k_permW(const float* __restrict__ W, float* __restrict__ Wp) {
    int i = blockIdx.x * blockDim.x + threadIdx.x;  // 65536 threads
    int o = i >> 8, k = i & 255;
    int p = (k & 3) * 64 + (k >> 2);
    Wp[o * 256 + p] = W[i];
}

// Fused: edge-parallel gather into swizzled LDS agg (ds_add_f32), then
// register-blocked fp32 GEMM vs pre-permuted W staged in 16-wide chunks.
__global__ __launch_bounds__(256, 3) void k_fused(
    const float* __restrict__ x, const int2* __restrict__ sedge,
    const int* __restrict__ row_start, const float* __restrict__ Wp,
    const float* __restrict__ bias, float* __restrict__ out, int n) {
    // 32*260*4 = 33280 B ; 256*20*4 = 20480 B ; total 53760 B -> 3 blocks/CU
    __shared__ __align__(16) float agg_s[NPB][D + 4];
    __shared__ __align__(16) float wsm[256][20];

    const int tid = threadIdx.x;
    const int lane = tid & 63;
    const int wv = tid >> 6;
    float* aggf = &agg_s[0][0];

    // zero agg (ws/LDS start poisoned)
    for (int i = tid; i < NPB * (D + 4); i += 256) aggf[i] = 0.f;
    __syncthreads();

    // ---------- phase 1: edge-parallel gather ----------
    const int b0 = blockIdx.x * NPB;
    const int e_lo = row_start[b0];
    const int e_hi = row_start[b0 + NPB];
    const float4* xb = (const float4*)x;

    // each wave: pairs (e, e+1) starting at e_lo + wv*2, stride 8; depth-2 pipeline
    int e = e_lo + wv * 2;
    int2 ev0, ev1;
    float4 xv0, xv1;
    bool p1 = false;
    if (e < e_hi) {
        ev0 = sedge[e];
        p1 = (e + 1) < e_hi;
        if (p1) ev1 = sedge[e + 1];
        xv0 = xb[(size_t)(ev0.x & COLMASK) * 64 + lane];
        if (p1) xv1 = xb[(size_t)(ev1.x & COLMASK) * 64 + lane];
    }
    while (e < e_hi) {
        int en = e + 8;
        int2 en0, en1;
        float4 xn0, xn1;
        bool q0 = en < e_hi;
        bool q1 = (en + 1) < e_hi;
        if (q0) {
            en0 = sedge[en];
            if (q1) en1 = sedge[en + 1];
            xn0 = xb[(size_t)(en0.x & COLMASK) * 64 + lane];
            if (q1) xn1 = xb[(size_t)(en1.x & COLMASK) * 64 + lane];
        }
        {   // commit edge e (always valid inside loop)
            float v = __int_as_float(ev0.y);
            int m = ((unsigned)ev0.x) >> 27;
            float* a = aggf + m * (D + 4) + lane;  // p = r*64 + lane, 2-way banks: free
            atomicAdd(a, v * xv0.x);
            atomicAdd(a + 64, v * xv0.y);
            atomicAdd(a + 128, v * xv0.z);
            atomicAdd(a + 192, v * xv0.w);
        }
        if (p1) {  // commit edge e+1
            float v = __int_as_float(ev1.y);
            int m = ((unsigned)ev1.x) >> 27;
            float* a = aggf + m * (D + 4) + lane;
            atomicAdd(a, v * xv1.x);
            atomicAdd(a + 64, v * xv1.y);
            atomicAdd(a + 128, v * xv1.z);
            atomicAdd(a + 192, v * xv1.w);
        }
        e = en;
        ev0 = en0; ev1 = en1; xv0 = xn0; xv1 = xn1; p1 = q1;
    }

    // ---------- phase 2: out[m][o] = sum_p agg[m][p] * Wp[o][p] + b[o] ----------
    const int tx = tid & 15;  // o = tx + 16*i
    const int ty = tid >> 4;  // m = ty*2 + j
    float acc2[2][16];
#pragma unroll
    for (int j = 0; j < 2; ++j)
#pragma unroll
        for (int i = 0; i < 16; ++i) acc2[j][i] = 0.f;

    for (int kc = 0; kc < 16; ++kc) {  // p-chunks of 16
        __syncthreads();               // also orders phase-1 ds_adds before reads
#pragma unroll
        for (int r = 0; r < 4; ++r) {
            int o = (tid >> 2) + (r << 6);
            int kk = (tid & 3) << 2;
            float4 wv4 = *(const float4*)&Wp[(size_t)o * D + kc * 16 + kk];
            *(float4*)&wsm[o][kk] = wv4;
        }
        __syncthreads();
#pragma unroll
        for (int k4 = 0; k4 < 4; ++k4) {
            float4 a0 = *(const float4*)&agg_s[ty * 2 + 0][kc * 16 + k4 * 4];
            float4 a1 = *(const float4*)&agg_s[ty * 2 + 1][kc * 16 + k4 * 4];
#pragma unroll
            for (int i = 0; i < 16; ++i) {
                float4 w4 = *(const float4*)&wsm[tx + 16 * i][k4 * 4];
                acc2[0][i] += a0.x * w4.x + a0.y * w4.y + a0.z * w4.z + a0.w * w4.w;
                acc2[1][i] += a1.x * w4.x + a1.y * w4.y + a1.z * w4.z + a1.w * w4.w;
            }
        }
    }

#pragma unroll
    for (int j = 0; j < 2; ++j) {
        int node = blockIdx.x * NPB + ty * 2 + j;
        if (node < n) {
            float* op = out + (size_t)node * D;
#pragma unroll
            for (int i = 0; i < 16; ++i) {
                int o = tx + 16 * i;
                op[o] = acc2[j][i] + bias[o];
            }
        }
    }
}

extern "C" void kernel_launch(void* const* d_in, const int* in_sizes, int n_in,
                              void* d_out, int out_size, void* d_ws, size_t ws_size,
                              hipStream_t stream) {
    const float* x    = (const float*)d_in[0];
    const int*   erow = (const int*)d_in[1];
    const int*   ecol = (const int*)d_in[2];
    const float* eval = (const float*)d_in[3];
    const float* W    = (const float*)d_in[4];
    const float* bias = (const float*)d_in[5];
    float* out = (float*)d_out;

    const int n = in_sizes[0] / D;  // 100000
    const int e = in_sizes[1];      // 3200000

    // ws: counts[n] | cursor[n] | blk_sums[64] | row_start[n+1] | sedge[e] (int2) | Wp[65536]
    int* counts    = (int*)d_ws;
    int* cursor    = counts + n;
    int* blk_sums  = cursor + n;
    int* row_start = blk_sums + 64;
    int2* sedge    = (int2*)(((uintptr_t)(row_start + n + 1) + 15) & ~(uintptr_t)15);
    float* Wp      = (float*)(sedge + e);

    hipMemsetAsync(counts, 0, (size_t)(2 * n + 64) * sizeof(int), stream);

    const int nch = (n + SCAN_CHUNK - 1) / SCAN_CHUNK;  // 49

    k_hist<<<(e + 255) / 256, 256, 0, stream>>>(erow, counts, e);
    k_scan1<<<nch, 256, 0, stream>>>(counts, row_start, blk_sums, n);
    k_scan2<<<1, 64, 0, stream>>>(blk_sums, row_start, nch, n);
    k_scan3<<<(n + 255) / 256, 256, 0, stream>>>(row_start, blk_sums, n);
    k_permW<<<256, 256, 0, stream>>>(W, Wp);
    k_scatter<<<(e + 255) / 256, 256, 0, stream>>>(erow, ecol, eval, row_start, cursor, sedge, e);
    k_fused<<<(n + NPB - 1) / NPB, 256, 0, stream>>>(x, sedge, row_start, Wp, bias, out, n);
}

// Round 3
// 1666.334 us; speedup vs baseline: 2.9764x; 2.9764x over previous
//
#include <hip/hip_runtime.h>
#include <cstdint>
#include <cstddef>

// GraphConvolution: out = (A_sparse @ x) @ W^T + b
// N=100000, E=3.2M, D=256.
// Pipeline: histogram -> scan -> CSR scatter -> fused gather+linear.
// Gather: each wave owns 8 nodes, processed IN PARALLEL (8 independent
// load chains per iteration) for memory-level parallelism. Branch-free:
// clamped indices + wave-uniform masks (R2's divergent pipeline spilled).
#define D 256
#define NPB 32           // nodes per fused block (100000 % 32 == 0)
#define SCAN_CHUNK 2048  // 256 threads * 8 items

__global__ void k_hist(const int* __restrict__ erow, int* __restrict__ counts, int e) {
    int i = blockIdx.x * blockDim.x + threadIdx.x;
    if (i < e) atomicAdd(&counts[erow[i]], 1);
}

__global__ void k_scan1(const int* __restrict__ counts, int* __restrict__ row_start,
                        int* __restrict__ blk_sums, int n) {
    __shared__ int sd[256];
    int tid = threadIdx.x;
    int base = blockIdx.x * SCAN_CHUNK + tid * 8;
    int v[8];
    int s = 0;
#pragma unroll
    for (int i = 0; i < 8; ++i) {
        int idx = base + i;
        v[i] = (idx < n) ? counts[idx] : 0;
        s += v[i];
    }
    sd[tid] = s;
    __syncthreads();
    for (int off = 1; off < 256; off <<= 1) {
        int t = (tid >= off) ? sd[tid - off] : 0;
        __syncthreads();
        sd[tid] += t;
        __syncthreads();
    }
    int run = sd[tid] - s;
    if (tid == 255) blk_sums[blockIdx.x] = sd[255];
#pragma unroll
    for (int i = 0; i < 8; ++i) {
        int idx = base + i;
        if (idx < n) row_start[idx] = run;
        run += v[i];
    }
}

__global__ void k_scan2(int* __restrict__ blk_sums, int* __restrict__ row_start, int nch, int n) {
    __shared__ int sd[64];
    int tid = threadIdx.x;
    if (tid < nch) sd[tid] = blk_sums[tid];
    __syncthreads();
    if (tid == 0) {
        int run = 0;
        for (int b = 0; b < nch; ++b) { int t = sd[b]; sd[b] = run; run += t; }
        row_start[n] = run;  // == E
    }
    __syncthreads();
    if (tid < nch) blk_sums[tid] = sd[tid];
}

__global__ void k_scan3(int* __restrict__ row_start, const int* __restrict__ blk_sums, int n) {
    int i = blockIdx.x * blockDim.x + threadIdx.x;
    if (i < n) row_start[i] += blk_sums[i >> 11];
}

__global__ void k_scatter(const int* __restrict__ erow, const int* __restrict__ ecol,
                          const float* __restrict__ eval, const int* __restrict__ row_start,
                          int* __restrict__ cursor, int2* __restrict__ sedge, int e) {
    int i = blockIdx.x * blockDim.x + threadIdx.x;
    if (i < e) {
        int r = erow[i];
        int p = row_start[r] + atomicAdd(&cursor[r], 1);
        sedge[p] = make_int2(ecol[i], __float_as_int(eval[i]));
    }
}

// Fused: 8-node-parallel gather per wave (register acc), then register-blocked
// fp32 GEMM vs W staged in LDS 16-wide k-chunks.
__global__ __launch_bounds__(256, 3) void k_fused(
    const float* __restrict__ x, const int2* __restrict__ sedge,
    const int* __restrict__ row_start, const float* __restrict__ W,
    const float* __restrict__ bias, float* __restrict__ out, int n) {
    // 32*260*4 = 33280 B ; 256*20*4 = 20480 B ; total 53760 B
    __shared__ __align__(16) float agg_s[NPB][D + 4];
    __shared__ __align__(16) float wsm[256][20];

    const int tid = threadIdx.x;
    const int lane = tid & 63;
    const int wv = tid >> 6;

    // ---------- phase 1: gather, 8 parallel chains per wave ----------
    const int base_node = blockIdx.x * NPB + wv * 8;
    int ebeg[8], eend[8];
    int maxd = 0;
#pragma unroll
    for (int j = 0; j < 8; ++j) {
        ebeg[j] = row_start[base_node + j];
        eend[j] = row_start[base_node + j + 1];
        maxd = max(maxd, eend[j] - ebeg[j]);
    }
    float4 acc[8];
#pragma unroll
    for (int j = 0; j < 8; ++j) acc[j] = make_float4(0.f, 0.f, 0.f, 0.f);

    const float4* xb = (const float4*)x;
    for (int it = 0; it < maxd; ++it) {
        int2 ev[8];
        float4 xv[8];
#pragma unroll
        for (int j = 0; j < 8; ++j) {
            int e = ebeg[j] + it;
            int ec = max(min(e, eend[j] - 1), 0);  // clamp: always a valid load
            ev[j] = sedge[ec];
        }
#pragma unroll
        for (int j = 0; j < 8; ++j) {
            xv[j] = xb[(size_t)ev[j].x * (D / 4) + lane];  // coalesced 1KB/wave
        }
#pragma unroll
        for (int j = 0; j < 8; ++j) {
            // wave-uniform mask (all lanes same node) -> no divergence
            float v = (ebeg[j] + it < eend[j]) ? __int_as_float(ev[j].y) : 0.f;
            acc[j].x += v * xv[j].x;
            acc[j].y += v * xv[j].y;
            acc[j].z += v * xv[j].z;
            acc[j].w += v * xv[j].w;
        }
    }
#pragma unroll
    for (int j = 0; j < 8; ++j) {
        *(float4*)&agg_s[wv * 8 + j][lane * 4] = acc[j];  // b128, row pad 260
    }

    // ---------- phase 2: out[m][o] = sum_k agg[m][k] * W[o][k] + b[o] ----------
    const int tx = tid & 15;  // o = tx + 16*i
    const int ty = tid >> 4;  // m = ty*2 + j
    float acc2[2][16];
#pragma unroll
    for (int j = 0; j < 2; ++j)
#pragma unroll
        for (int i = 0; i < 16; ++i) acc2[j][i] = 0.f;

    for (int kc = 0; kc < 16; ++kc) {  // k-chunks of 16
        __syncthreads();               // (first one also closes phase 1)
#pragma unroll
        for (int r = 0; r < 4; ++r) {
            int o = (tid >> 2) + (r << 6);
            int kk = (tid & 3) << 2;
            float4 wv4 = *(const float4*)&W[(size_t)o * D + kc * 16 + kk];
            *(float4*)&wsm[o][kk] = wv4;
        }
        __syncthreads();
#pragma unroll
        for (int k4 = 0; k4 < 4; ++k4) {
            float4 a0 = *(const float4*)&agg_s[ty * 2 + 0][kc * 16 + k4 * 4];
            float4 a1 = *(const float4*)&agg_s[ty * 2 + 1][kc * 16 + k4 * 4];
#pragma unroll
            for (int i = 0; i < 16; ++i) {
                float4 w4 = *(const float4*)&wsm[tx + 16 * i][k4 * 4];
                acc2[0][i] += a0.x * w4.x + a0.y * w4.y + a0.z * w4.z + a0.w * w4.w;
                acc2[1][i] += a1.x * w4.x + a1.y * w4.y + a1.z * w4.z + a1.w * w4.w;
            }
        }
    }

#pragma unroll
    for (int j = 0; j < 2; ++j) {
        int node = blockIdx.x * NPB + ty * 2 + j;
        if (node < n) {
            float* op = out + (size_t)node * D;
#pragma unroll
            for (int i = 0; i < 16; ++i) {
                int o = tx + 16 * i;
                op[o] = acc2[j][i] + bias[o];
            }
        }
    }
}

extern "C" void kernel_launch(void* const* d_in, const int* in_sizes, int n_in,
                              void* d_out, int out_size, void* d_ws, size_t ws_size,
                              hipStream_t stream) {
    const float* x    = (const float*)d_in[0];
    const int*   erow = (const int*)d_in[1];
    const int*   ecol = (const int*)d_in[2];
    const float* eval = (const float*)d_in[3];
    const float* W    = (const float*)d_in[4];
    const float* bias = (const float*)d_in[5];
    float* out = (float*)d_out;

    const int n = in_sizes[0] / D;  // 100000
    const int e = in_sizes[1];      // 3200000

    // ws: counts[n] | cursor[n] | blk_sums[64] | row_start[n+1] | sedge[e] (int2)
    int* counts    = (int*)d_ws;
    int* cursor    = counts + n;
    int* blk_sums  = cursor + n;
    int* row_start = blk_sums + 64;
    int2* sedge    = (int2*)(((uintptr_t)(row_start + n + 1) + 15) & ~(uintptr_t)15);

    hipMemsetAsync(counts, 0, (size_t)(2 * n + 64) * sizeof(int), stream);

    const int nch = (n + SCAN_CHUNK - 1) / SCAN_CHUNK;  // 49

    k_hist<<<(e + 255) / 256, 256, 0, stream>>>(erow, counts, e);
    k_scan1<<<nch, 256, 0, stream>>>(counts, row_start, blk_sums, n);
    k_scan2<<<1, 64, 0, stream>>>(blk_sums, row_start, nch, n);
    k_scan3<<<(n + 255) / 256, 256, 0, stream>>>(row_start, blk_sums, n);
    k_scatter<<<(e + 255) / 256, 256, 0, stream>>>(erow, ecol, eval, row_start, cursor, sedge, e);
    k_fused<<<(n + NPB - 1) / NPB, 256, 0, stream>>>(x, sedge, row_start, W, bias, out, n);
}

// Round 4
// 993.850 us; speedup vs baseline: 4.9903x; 1.6766x over previous
//
#include <hip/hip_runtime.h>
#include <cstdint>
#include <cstddef>

// GraphConvolution: out = (A_sparse @ x) @ W^T + b   (N=100000, E=3.2M, D=256)
// Pipeline: hist -> scan -> CSR scatter -> gather (reg acc, bf16 agg out)
//           -> bf16 MFMA GEMM (agg @ W^T + b).
// NOTE: never use the 2nd __launch_bounds__ arg here — R2/R3 showed it caps
// VGPRs to ~84 and forces ~2.3 GB of scratch spill traffic in the gather.
#define D 256
#define NPB 32
#define SCAN_CHUNK 2048

typedef __attribute__((ext_vector_type(8))) short short8;
typedef __attribute__((ext_vector_type(4))) float floatx4;

__device__ __forceinline__ unsigned short f2bf(float f) {
    union { float f; unsigned int u; } cv; cv.f = f;
    unsigned int u = cv.u;
    unsigned int r = (u + 0x7fffu + ((u >> 16) & 1u)) >> 16;  // RNE
    return (unsigned short)r;
}

__global__ void k_hist(const int* __restrict__ erow, int* __restrict__ counts, int e) {
    int i = blockIdx.x * blockDim.x + threadIdx.x;
    if (i < e) atomicAdd(&counts[erow[i]], 1);
}

__global__ void k_scan1(const int* __restrict__ counts, int* __restrict__ row_start,
                        int* __restrict__ blk_sums, int n) {
    __shared__ int sd[256];
    int tid = threadIdx.x;
    int base = blockIdx.x * SCAN_CHUNK + tid * 8;
    int v[8];
    int s = 0;
#pragma unroll
    for (int i = 0; i < 8; ++i) {
        int idx = base + i;
        v[i] = (idx < n) ? counts[idx] : 0;
        s += v[i];
    }
    sd[tid] = s;
    __syncthreads();
    for (int off = 1; off < 256; off <<= 1) {
        int t = (tid >= off) ? sd[tid - off] : 0;
        __syncthreads();
        sd[tid] += t;
        __syncthreads();
    }
    int run = sd[tid] - s;
    if (tid == 255) blk_sums[blockIdx.x] = sd[255];
#pragma unroll
    for (int i = 0; i < 8; ++i) {
        int idx = base + i;
        if (idx < n) row_start[idx] = run;
        run += v[i];
    }
}

__global__ void k_scan2(int* __restrict__ blk_sums, int* __restrict__ row_start, int nch, int n) {
    __shared__ int sd[64];
    int tid = threadIdx.x;
    if (tid < nch) sd[tid] = blk_sums[tid];
    __syncthreads();
    if (tid == 0) {
        int run = 0;
        for (int b = 0; b < nch; ++b) { int t = sd[b]; sd[b] = run; run += t; }
        row_start[n] = run;
    }
    __syncthreads();
    if (tid < nch) blk_sums[tid] = sd[tid];
}

__global__ void k_scan3(int* __restrict__ row_start, const int* __restrict__ blk_sums, int n) {
    int i = blockIdx.x * blockDim.x + threadIdx.x;
    if (i < n) row_start[i] += blk_sums[i >> 11];
}

__global__ void k_scatter(const int* __restrict__ erow, const int* __restrict__ ecol,
                          const float* __restrict__ eval, const int* __restrict__ row_start,
                          int* __restrict__ cursor, int2* __restrict__ sedge, int e) {
    int i = blockIdx.x * blockDim.x + threadIdx.x;
    if (i < e) {
        int r = erow[i];
        int p = row_start[r] + atomicAdd(&cursor[r], 1);
        sedge[p] = make_int2(ecol[i], __float_as_int(eval[i]));
    }
}

__global__ void k_castW(const float* __restrict__ W, unsigned short* __restrict__ Wb) {
    int i = blockIdx.x * blockDim.x + threadIdx.x;  // 65536
    Wb[i] = f2bf(W[i]);
}

// Gather: each wave owns 8 nodes IN PARALLEL (8 independent load chains per
// iteration = MLP). No LDS, register accumulators, bf16 output rows.
__global__ __launch_bounds__(256) void k_gather(
    const float* __restrict__ x, const int2* __restrict__ sedge,
    const int* __restrict__ row_start, unsigned short* __restrict__ aggb, int n) {
    const int tid = threadIdx.x;
    const int lane = tid & 63;
    const int wv = tid >> 6;
    const int base_node = blockIdx.x * NPB + wv * 8;

    int ebeg[8], eend[8];
    int maxd = 0;
#pragma unroll
    for (int j = 0; j < 8; ++j) {
        ebeg[j] = row_start[base_node + j];
        eend[j] = row_start[base_node + j + 1];
        maxd = max(maxd, eend[j] - ebeg[j]);
    }
    float4 acc[8];
#pragma unroll
    for (int j = 0; j < 8; ++j) acc[j] = make_float4(0.f, 0.f, 0.f, 0.f);

    const float4* xb = (const float4*)x;
    for (int it = 0; it < maxd; ++it) {
        int2 ev[8];
        float4 xv[8];
#pragma unroll
        for (int j = 0; j < 8; ++j) {
            int e = ebeg[j] + it;
            int ec = max(min(e, eend[j] - 1), 0);  // clamped: always valid
            ev[j] = sedge[ec];
        }
#pragma unroll
        for (int j = 0; j < 8; ++j) {
            xv[j] = xb[(size_t)ev[j].x * (D / 4) + lane];  // 1KB/wave coalesced
        }
#pragma unroll
        for (int j = 0; j < 8; ++j) {
            float v = (ebeg[j] + it < eend[j]) ? __int_as_float(ev[j].y) : 0.f;
            acc[j].x += v * xv[j].x;
            acc[j].y += v * xv[j].y;
            acc[j].z += v * xv[j].z;
            acc[j].w += v * xv[j].w;
        }
    }
#pragma unroll
    for (int j = 0; j < 8; ++j) {
        ushort4 u;
        u.x = f2bf(acc[j].x);
        u.y = f2bf(acc[j].y);
        u.z = f2bf(acc[j].z);
        u.w = f2bf(acc[j].w);
        *(ushort4*)&aggb[(size_t)(base_node + j) * D + lane * 4] = u;  // 512B/row
    }
}

// GEMM: out[m][o] = sum_k aggb[m][k] * Wb[o][k] + bias[o], bf16 MFMA.
// Block = 4 waves x 16 rows = 64-row M-tile, full N=256, K chunked by 64.
// A-frag: A[m=lane&15][k=quad*8+j]; B-frag: B[k=quad*8+j][n=lane&15] with
// B[k][n] = W[n][k] (16B contiguous from row-major W). C/D: col=lane&15,
// row=quad*4+reg (m89-verified). LDS W rows padded to 72 bf16 -> balanced banks.
__global__ __launch_bounds__(256) void k_gemm(
    const unsigned short* __restrict__ aggb, const unsigned short* __restrict__ Wb,
    const float* __restrict__ bias, float* __restrict__ out, int M) {
    __shared__ __align__(16) unsigned short Wl[256 * 72];  // 36 KB

    const int tid = threadIdx.x;
    const int lane = tid & 63;
    const int wv = tid >> 6;
    const int col = lane & 15;
    const int quad = lane >> 4;
    const int bm = blockIdx.x * 64 + wv * 16;

    floatx4 acc[16];
#pragma unroll
    for (int i = 0; i < 16; ++i) acc[i] = (floatx4){0.f, 0.f, 0.f, 0.f};

    const int arow = min(bm + col, M - 1);  // clamp (stores are guarded)

    for (int kc = 0; kc < 4; ++kc) {
        __syncthreads();
        // stage W[0..255][kc*64 .. +63] -> Wl, thread t = row t (8x 16B)
        {
            const uint4* src = (const uint4*)(Wb + (size_t)tid * D + kc * 64);
#pragma unroll
            for (int s = 0; s < 8; ++s) {
                *(uint4*)&Wl[tid * 72 + s * 8] = src[s];
            }
        }
        __syncthreads();

        short8 a[2];
#pragma unroll
        for (int t2 = 0; t2 < 2; ++t2) {
            a[t2] = *(const short8*)&aggb[(size_t)arow * D + kc * 64 + t2 * 32 + quad * 8];
        }
#pragma unroll
        for (int i = 0; i < 16; ++i) {
#pragma unroll
            for (int t2 = 0; t2 < 2; ++t2) {
                short8 b = *(const short8*)&Wl[(i * 16 + col) * 72 + t2 * 32 + quad * 8];
                acc[i] = __builtin_amdgcn_mfma_f32_16x16x32_bf16(a[t2], b, acc[i], 0, 0, 0);
            }
        }
    }

#pragma unroll
    for (int i = 0; i < 16; ++i) {
        int o = i * 16 + col;
        float bv = bias[o];
#pragma unroll
        for (int r = 0; r < 4; ++r) {
            int m = bm + quad * 4 + r;
            if (m < M) out[(size_t)m * D + o] = acc[i][r] + bv;
        }
    }
}

extern "C" void kernel_launch(void* const* d_in, const int* in_sizes, int n_in,
                              void* d_out, int out_size, void* d_ws, size_t ws_size,
                              hipStream_t stream) {
    const float* x    = (const float*)d_in[0];
    const int*   erow = (const int*)d_in[1];
    const int*   ecol = (const int*)d_in[2];
    const float* eval = (const float*)d_in[3];
    const float* W    = (const float*)d_in[4];
    const float* bias = (const float*)d_in[5];
    float* out = (float*)d_out;

    const int n = in_sizes[0] / D;  // 100000
    const int e = in_sizes[1];      // 3200000

    // ws: counts[n] | cursor[n] | blk_sums[64] | row_start[n+1] | sedge[e] int2
    //     | Wb[65536] u16 | aggb[n*256] u16   (~78 MB total)
    int* counts    = (int*)d_ws;
    int* cursor    = counts + n;
    int* blk_sums  = cursor + n;
    int* row_start = blk_sums + 64;
    int2* sedge    = (int2*)(((uintptr_t)(row_start + n + 1) + 15) & ~(uintptr_t)15);
    unsigned short* Wb   = (unsigned short*)(sedge + e);
    unsigned short* aggb = Wb + 65536;

    hipMemsetAsync(counts, 0, (size_t)(2 * n + 64) * sizeof(int), stream);

    const int nch = (n + SCAN_CHUNK - 1) / SCAN_CHUNK;  // 49

    k_hist<<<(e + 255) / 256, 256, 0, stream>>>(erow, counts, e);
    k_scan1<<<nch, 256, 0, stream>>>(counts, row_start, blk_sums, n);
    k_scan2<<<1, 64, 0, stream>>>(blk_sums, row_start, nch, n);
    k_scan3<<<(n + 255) / 256, 256, 0, stream>>>(row_start, blk_sums, n);
    k_castW<<<256, 256, 0, stream>>>(W, Wb);
    k_scatter<<<(e + 255) / 256, 256, 0, stream>>>(erow, ecol, eval, row_start, cursor, sedge, e);
    k_gather<<<n / NPB, 256, 0, stream>>>(x, sedge, row_start, aggb, n);
    k_gemm<<<(n + 63) / 64, 256, 0, stream>>>(aggb, Wb, bias, out, n);
}